// Round 1
// baseline (377.312 us; speedup 1.0000x reference)
//
#include <hip/hip_runtime.h>
#include <math.h>

#define NQ 16384
#define NS 4096
#define NCH 256
#define BIGD 1e8f
#define EPSW 1e-8f

// ---------------------------------------------------------------- KNN ------
// 256 blocks x 256 threads. Each block handles 64 query points; the 4 waves
// of the block each scan a quarter of the 4096 source points (staged in LDS
// as float4 {x,y,z,pid}), then partial top-3s are merged by the first wave.
__global__ __launch_bounds__(256)
void knn_kernel(const float* __restrict__ xyz1, const float* __restrict__ xyz2,
                const int* __restrict__ pid1, const int* __restrict__ pid2,
                int* __restrict__ oidx, float* __restrict__ ow)
{
    __shared__ float4 sp[NS];             // 64 KB, reused as merge buffer
    const int tid = threadIdx.x;
    for (int i = tid; i < NS; i += 256) {
        sp[i] = make_float4(xyz2[i], xyz2[NS + i], xyz2[2 * NS + i],
                            __int_as_float(pid2[i]));
    }
    __syncthreads();

    const int lane = tid & 63;
    const int part = tid >> 6;            // wave id 0..3
    const int q = blockIdx.x * 64 + lane;
    const float qx = xyz1[q], qy = xyz1[NQ + q], qz = xyz1[2 * NQ + q];
    const int qid = pid1[q];

    float d0 = INFINITY, d1 = INFINITY, d2 = INFINITY;
    int i0 = 0, i1 = 0, i2 = 0;
    const int sBeg = part * (NS / 4), sEnd = sBeg + (NS / 4);
    for (int s = sBeg; s < sEnd; ++s) {
        float4 p = sp[s];                 // wave-uniform address -> broadcast
        float dx = p.x - qx, dy = p.y - qy, dz = p.z - qz;
        float d = fmaf(dz, dz, fmaf(dy, dy, dx * dx));
        if (__float_as_int(p.w) != qid) d = INFINITY;
        if (d < d2) {                     // strict < keeps lowest-index ties
            if (d < d1) {
                d2 = d1; i2 = i1;
                if (d < d0) { d1 = d0; i1 = i0; d0 = d; i0 = s; }
                else        { d1 = d;  i1 = s; }
            } else { d2 = d; i2 = s; }
        }
    }
    __syncthreads();                      // everyone done reading sp
    float2* cand = (float2*)sp;
    const int cb = (lane * 4 + part) * 3;
    cand[cb + 0] = make_float2(d0, __int_as_float(i0));
    cand[cb + 1] = make_float2(d1, __int_as_float(i1));
    cand[cb + 2] = make_float2(d2, __int_as_float(i2));
    __syncthreads();

    if (tid < 64) {
        d0 = d1 = d2 = INFINITY; i0 = i1 = i2 = 0;
        for (int p = 0; p < 4; ++p) {     // part order = ascending index order
            #pragma unroll
            for (int k = 0; k < 3; ++k) {
                float2 c = cand[(tid * 4 + p) * 3 + k];
                float d = c.x; int s = __float_as_int(c.y);
                if (d < d2) {
                    if (d < d1) {
                        d2 = d1; i2 = i1;
                        if (d < d0) { d1 = d0; i1 = i0; d0 = d; i0 = s; }
                        else        { d1 = d;  i1 = s; }
                    } else { d2 = d; i2 = s; }
                }
            }
        }
        // fill_value semantics: invalid slots reuse idx0 with BIG distance
        if (isinf(d0)) { i0 = 0;  d0 = BIGD; }
        if (isinf(d1)) { i1 = i0; d1 = BIGD; }
        if (isinf(d2)) { i2 = i0; d2 = BIGD; }
        float w0 = 1.f / (d0 + EPSW), w1 = 1.f / (d1 + EPSW), w2 = 1.f / (d2 + EPSW);
        float inv = 1.f / (w0 + w1 + w2);
        const int qg = blockIdx.x * 64 + tid;
        oidx[qg * 3 + 0] = i0; oidx[qg * 3 + 1] = i1; oidx[qg * 3 + 2] = i2;
        ow[qg * 3 + 0] = w0 * inv; ow[qg * 3 + 1] = w1 * inv; ow[qg * 3 + 2] = w2 * inv;
    }
}

// --------------------------------------------------------- interpolation ---
// interp[d][n] = sum_k w[n][k] * points2[d][idx[n][k]]
__global__ __launch_bounds__(256)
void interp_kernel(const float* __restrict__ points2, const int* __restrict__ oidx,
                   const float* __restrict__ ow, float* __restrict__ interp)
{
    const int n = blockIdx.x * 256 + threadIdx.x;
    const int d = blockIdx.y;
    const int i0 = oidx[n * 3 + 0], i1 = oidx[n * 3 + 1], i2 = oidx[n * 3 + 2];
    const float w0 = ow[n * 3 + 0], w1 = ow[n * 3 + 1], w2 = ow[n * 3 + 2];
    const float* row = points2 + (size_t)d * NS;
    interp[(size_t)d * NQ + n] = w0 * row[i0] + w1 * row[i1] + w2 * row[i2];
}

// ------------------------------------------------------------------ GEMM ---
// C[256][NQ] = A[256][K] @ B[K][NQ]; B rows <256 from B0, >=256 from B1.
// 128x128 tile per 256-thread block, Kt=8, 8x8 accumulators per thread.
template<int K, bool DUAL>
__global__ __launch_bounds__(256)
void gemm_kernel(const float* __restrict__ A, const float* __restrict__ B0,
                 const float* __restrict__ B1, float* __restrict__ C)
{
    __shared__ float as[8][128];
    __shared__ float bs[8][132];
    const int tid = threadIdx.x;
    const int mtile = blockIdx.x >> 7;     // 2 m-tiles
    const int ntile = blockIdx.x & 127;    // 128 n-tiles
    const int m0 = mtile * 128, n0 = ntile * 128;
    const int tx = tid & 15, ty = tid >> 4;
    const int ar = tid >> 1, ac = (tid & 1) * 4;
    const int br = tid >> 5, bc = (tid & 31) * 4;
    float acc[8][8] = {};
    for (int k0 = 0; k0 < K; k0 += 8) {
        __syncthreads();
        float4 av = *(const float4*)&A[(size_t)(m0 + ar) * K + k0 + ac];
        as[ac + 0][ar] = av.x; as[ac + 1][ar] = av.y;
        as[ac + 2][ar] = av.z; as[ac + 3][ar] = av.w;
        const int kr = k0 + br;
        const float* Brow = (!DUAL || kr < 256)
                              ? (B0 + (size_t)kr * NQ)
                              : (B1 + (size_t)(kr - 256) * NQ);
        *(float4*)&bs[br][bc] = *(const float4*)&Brow[n0 + bc];
        __syncthreads();
        #pragma unroll
        for (int k = 0; k < 8; ++k) {
            float a[8], b[8];
            *(float4*)&a[0] = *(const float4*)&as[k][ty * 8];
            *(float4*)&a[4] = *(const float4*)&as[k][ty * 8 + 4];
            *(float4*)&b[0] = *(const float4*)&bs[k][tx * 8];
            *(float4*)&b[4] = *(const float4*)&bs[k][tx * 8 + 4];
            #pragma unroll
            for (int i = 0; i < 8; ++i)
                #pragma unroll
                for (int j = 0; j < 8; ++j)
                    acc[i][j] = fmaf(a[i], b[j], acc[i][j]);
        }
    }
    #pragma unroll
    for (int i = 0; i < 8; ++i) {
        float* crow = C + (size_t)(m0 + ty * 8 + i) * NQ + n0 + tx * 8;
        *(float4*)&crow[0] = *(float4*)&acc[i][0];
        *(float4*)&crow[4] = *(float4*)&acc[i][4];
    }
}

// -------------------------------------------------------------- batchnorm --
// One block per channel: mean/E[x^2] over NQ, then scale/shift with the
// conv bias folded out (it cancels in y - mean).
__global__ __launch_bounds__(256)
void bn_stats_kernel(const float* __restrict__ Y, const float* __restrict__ g,
                     const float* __restrict__ bt, float* __restrict__ scale,
                     float* __restrict__ shift)
{
    const int c = blockIdx.x;
    const float4* row = (const float4*)(Y + (size_t)c * NQ);
    float s = 0.f, ss = 0.f;
    for (int i = threadIdx.x; i < NQ / 4; i += 256) {
        float4 v = row[i];
        s  += v.x + v.y + v.z + v.w;
        ss += v.x * v.x + v.y * v.y + v.z * v.z + v.w * v.w;
    }
    #pragma unroll
    for (int off = 32; off; off >>= 1) {
        s  += __shfl_down(s, off);
        ss += __shfl_down(ss, off);
    }
    __shared__ float red[4][2];
    const int w = threadIdx.x >> 6;
    if ((threadIdx.x & 63) == 0) { red[w][0] = s; red[w][1] = ss; }
    __syncthreads();
    if (threadIdx.x == 0) {
        s  = red[0][0] + red[1][0] + red[2][0] + red[3][0];
        ss = red[0][1] + red[1][1] + red[2][1] + red[3][1];
        float mean = s * (1.f / NQ);
        float var  = ss * (1.f / NQ) - mean * mean;
        float rstd = rsqrtf(var + 1e-5f);
        float sc = g[c] * rstd;
        scale[c] = sc;
        shift[c] = bt[c] - mean * sc;
    }
}

__global__ __launch_bounds__(256)
void bn_apply_kernel(float* __restrict__ Y, const float* __restrict__ scale,
                     const float* __restrict__ shift)
{
    const int i = blockIdx.x * 256 + threadIdx.x;  // float4 index
    const int c = i >> 12;                          // NQ/4 = 4096 per channel
    float4 v = ((float4*)Y)[i];
    const float sc = scale[c], sh = shift[c];
    v.x = fmaxf(fmaf(v.x, sc, sh), 0.f);
    v.y = fmaxf(fmaf(v.y, sc, sh), 0.f);
    v.z = fmaxf(fmaf(v.z, sc, sh), 0.f);
    v.w = fmaxf(fmaf(v.w, sc, sh), 0.f);
    ((float4*)Y)[i] = v;
}

// ------------------------------------------------------------------ launch -
extern "C" void kernel_launch(void* const* d_in, const int* in_sizes, int n_in,
                              void* d_out, int out_size, void* d_ws, size_t ws_size,
                              hipStream_t stream)
{
    const float* xyz1    = (const float*)d_in[0];
    const float* xyz2    = (const float*)d_in[1];
    const int*   pid1    = (const int*)d_in[2];
    const int*   pid2    = (const int*)d_in[3];
    const float* points1 = (const float*)d_in[4];
    const float* points2 = (const float*)d_in[5];
    const float* w0      = (const float*)d_in[6];
    const float* g0      = (const float*)d_in[8];
    const float* bt0     = (const float*)d_in[9];
    const float* w1      = (const float*)d_in[10];
    const float* g1      = (const float*)d_in[12];
    const float* bt1     = (const float*)d_in[13];
    float* out = (float*)d_out;

    char* ws = (char*)d_ws;
    int*   idxb   = (int*)(ws + 0);                       // 196608 B
    float* wb     = (float*)(ws + 196608);                // 196608 B
    float* interp = (float*)(ws + 393216);                // 16 MB
    float* y0     = (float*)(ws + 393216 + 16777216);     // 16 MB
    float* sc0    = (float*)(ws + 393216 + 2 * 16777216);
    float* sh0    = sc0 + NCH;
    float* sc1    = sh0 + NCH;
    float* sh1    = sc1 + NCH;

    knn_kernel<<<NQ / 64, 256, 0, stream>>>(xyz1, xyz2, pid1, pid2, idxb, wb);
    interp_kernel<<<dim3(NQ / 256, NCH), 256, 0, stream>>>(points2, idxb, wb, interp);
    gemm_kernel<512, true><<<256, 256, 0, stream>>>(w0, points1, interp, y0);
    bn_stats_kernel<<<NCH, 256, 0, stream>>>(y0, g0, bt0, sc0, sh0);
    bn_apply_kernel<<<(NCH * NQ / 4) / 256, 256, 0, stream>>>(y0, sc0, sh0);
    gemm_kernel<256, false><<<256, 256, 0, stream>>>(w1, y0, nullptr, out);
    bn_stats_kernel<<<NCH, 256, 0, stream>>>(out, g1, bt1, sc1, sh1);
    bn_apply_kernel<<<(NCH * NQ / 4) / 256, 256, 0, stream>>>(out, sc1, sh1);
}

// Round 2
// 304.640 us; speedup vs baseline: 1.2385x; 1.2385x over previous
//
#include <hip/hip_runtime.h>
#include <math.h>

#define NQ 16384
#define NS 4096
#define NCH 256
#define BIGD 1e8f
#define EPSW 1e-8f

// ---------------------------------------------------------------- KNN ------
// 512 blocks x 512 threads. Each block handles 32 queries; the source set is
// staged once in LDS (float4 {x,y,z,pid}, 64 KB) and split 16 ways across
// threads (256 points each). Branchless top-3 insert; padded LDS merge.
#define QB 32
#define SS 16
#define PPT (NS / SS)          // 256 points per thread
#define CSTRIDE (SS * 3 + 1)   // 49 float2 per query (pad kills bank conflict)

__global__ __launch_bounds__(512)
void knn_kernel(const float* __restrict__ xyz1, const float* __restrict__ xyz2,
                const int* __restrict__ pid1, const int* __restrict__ pid2,
                int* __restrict__ oidx, float* __restrict__ ow)
{
    __shared__ float4 sp[NS];             // 64 KB, reused as merge buffer
    const int tid = threadIdx.x;
    #pragma unroll
    for (int j = 0; j < 8; ++j) {
        const int i = tid + j * 512;
        sp[i] = make_float4(xyz2[i], xyz2[NS + i], xyz2[2 * NS + i],
                            __int_as_float(pid2[i]));
    }
    __syncthreads();

    const int ql = tid & 31;              // query within block
    const int part = tid >> 5;            // S-partition 0..15 (wave spans 2)
    const int q = blockIdx.x * QB + ql;
    const float qx = xyz1[q], qy = xyz1[NQ + q], qz = xyz1[2 * NQ + q];
    const int qid = pid1[q];

    float e0 = INFINITY, e1 = INFINITY, e2 = INFINITY;
    int j0 = 0, j1 = 0, j2 = 0;
    const int sBeg = part * PPT;
    #pragma unroll 4
    for (int i = 0; i < PPT; ++i) {
        const int s = sBeg + i;
        float4 p = sp[s];
        float dx = p.x - qx, dy = p.y - qy, dz = p.z - qz;
        float d = fmaf(dx, dx, fmaf(dy, dy, dz * dz));
        if (__float_as_int(p.w) != qid) d = INFINITY;
        // branchless strict-< insert (lowest index wins ties)
        const bool m0 = d < e0, m1 = d < e1, m2 = d < e2;
        const float ne2 = m1 ? e1 : d;  const int nj2 = m1 ? j1 : s;
        const float ne1 = m0 ? e0 : d;  const int nj1 = m0 ? j0 : s;
        e2 = m2 ? ne2 : e2;  j2 = m2 ? nj2 : j2;
        e1 = m1 ? ne1 : e1;  j1 = m1 ? nj1 : j1;
        e0 = m0 ? d : e0;    j0 = m0 ? s : j0;
    }
    __syncthreads();                      // done reading sp
    float2* cand = (float2*)sp;
    const int cb = ql * CSTRIDE + part * 3;
    cand[cb + 0] = make_float2(e0, __int_as_float(j0));
    cand[cb + 1] = make_float2(e1, __int_as_float(j1));
    cand[cb + 2] = make_float2(e2, __int_as_float(j2));
    __syncthreads();

    if (tid < QB) {
        e0 = e1 = e2 = INFINITY; j0 = j1 = j2 = 0;
        const float2* row = cand + tid * CSTRIDE;
        for (int p = 0; p < SS; ++p) {    // ascending part = ascending index
            #pragma unroll
            for (int k = 0; k < 3; ++k) {
                float2 c = row[p * 3 + k];
                const float d = c.x; const int s = __float_as_int(c.y);
                const bool m0 = d < e0, m1 = d < e1, m2 = d < e2;
                const float ne2 = m1 ? e1 : d;  const int nj2 = m1 ? j1 : s;
                const float ne1 = m0 ? e0 : d;  const int nj1 = m0 ? j0 : s;
                e2 = m2 ? ne2 : e2;  j2 = m2 ? nj2 : j2;
                e1 = m1 ? ne1 : e1;  j1 = m1 ? nj1 : j1;
                e0 = m0 ? d : e0;    j0 = m0 ? s : j0;
            }
        }
        // fill_value semantics: invalid slots reuse idx0 with BIG distance
        if (isinf(e0)) { j0 = 0;  e0 = BIGD; }
        if (isinf(e1)) { j1 = j0; e1 = BIGD; }
        if (isinf(e2)) { j2 = j0; e2 = BIGD; }
        const float w0 = 1.f / (e0 + EPSW), w1 = 1.f / (e1 + EPSW), w2 = 1.f / (e2 + EPSW);
        const float inv = 1.f / (w0 + w1 + w2);
        const int qg = blockIdx.x * QB + tid;
        oidx[qg * 3 + 0] = j0; oidx[qg * 3 + 1] = j1; oidx[qg * 3 + 2] = j2;
        ow[qg * 3 + 0] = w0 * inv; ow[qg * 3 + 1] = w1 * inv; ow[qg * 3 + 2] = w2 * inv;
    }
}

// --------------------------------------------------------- interpolation ---
__global__ __launch_bounds__(256)
void interp_kernel(const float* __restrict__ points2, const int* __restrict__ oidx,
                   const float* __restrict__ ow, float* __restrict__ interp)
{
    const int n = blockIdx.x * 256 + threadIdx.x;
    const int d = blockIdx.y;
    const int i0 = oidx[n * 3 + 0], i1 = oidx[n * 3 + 1], i2 = oidx[n * 3 + 2];
    const float w0 = ow[n * 3 + 0], w1 = ow[n * 3 + 1], w2 = ow[n * 3 + 2];
    const float* row = points2 + (size_t)d * NS;
    interp[(size_t)d * NQ + n] = w0 * row[i0] + w1 * row[i1] + w2 * row[i2];
}

// ------------------------------------------------------------------ GEMM ---
// C[256][NQ] = A[256][K] @ B[K][NQ]; B rows <256 from B0, >=256 from B1.
// FUSE_BN: apply y = relu(b*sc[k]+sh[k]) to B elements while staging (folds
// the previous layer's batchnorm+relu into this GEMM's load).
template<int K, bool DUAL, bool FUSE_BN>
__global__ __launch_bounds__(256)
void gemm_kernel(const float* __restrict__ A, const float* __restrict__ B0,
                 const float* __restrict__ B1, const float* __restrict__ scB,
                 const float* __restrict__ shB, float* __restrict__ C)
{
    __shared__ float as[8][128];
    __shared__ float bs[8][132];
    const int tid = threadIdx.x;
    const int mtile = blockIdx.x >> 7;
    const int ntile = blockIdx.x & 127;
    const int m0 = mtile * 128, n0 = ntile * 128;
    const int tx = tid & 15, ty = tid >> 4;
    const int ar = tid >> 1, ac = (tid & 1) * 4;
    const int br = tid >> 5, bc = (tid & 31) * 4;
    float acc[8][8] = {};
    for (int k0 = 0; k0 < K; k0 += 8) {
        __syncthreads();
        float4 av = *(const float4*)&A[(size_t)(m0 + ar) * K + k0 + ac];
        as[ac + 0][ar] = av.x; as[ac + 1][ar] = av.y;
        as[ac + 2][ar] = av.z; as[ac + 3][ar] = av.w;
        const int kr = k0 + br;
        const float* Brow = (!DUAL || kr < 256)
                              ? (B0 + (size_t)kr * NQ)
                              : (B1 + (size_t)(kr - 256) * NQ);
        float4 bv = *(const float4*)&Brow[n0 + bc];
        if (FUSE_BN) {
            const float s = scB[kr], h = shB[kr];
            bv.x = fmaxf(fmaf(bv.x, s, h), 0.f);
            bv.y = fmaxf(fmaf(bv.y, s, h), 0.f);
            bv.z = fmaxf(fmaf(bv.z, s, h), 0.f);
            bv.w = fmaxf(fmaf(bv.w, s, h), 0.f);
        }
        *(float4*)&bs[br][bc] = bv;
        __syncthreads();
        #pragma unroll
        for (int k = 0; k < 8; ++k) {
            float a[8], b[8];
            *(float4*)&a[0] = *(const float4*)&as[k][ty * 8];
            *(float4*)&a[4] = *(const float4*)&as[k][ty * 8 + 4];
            *(float4*)&b[0] = *(const float4*)&bs[k][tx * 8];
            *(float4*)&b[4] = *(const float4*)&bs[k][tx * 8 + 4];
            #pragma unroll
            for (int i = 0; i < 8; ++i)
                #pragma unroll
                for (int j = 0; j < 8; ++j)
                    acc[i][j] = fmaf(a[i], b[j], acc[i][j]);
        }
    }
    #pragma unroll
    for (int i = 0; i < 8; ++i) {
        float* crow = C + (size_t)(m0 + ty * 8 + i) * NQ + n0 + tx * 8;
        *(float4*)&crow[0] = *(float4*)&acc[i][0];
        *(float4*)&crow[4] = *(float4*)&acc[i][4];
    }
}

// -------------------------------------------------------------- batchnorm --
__global__ __launch_bounds__(256)
void bn_stats_kernel(const float* __restrict__ Y, const float* __restrict__ g,
                     const float* __restrict__ bt, float* __restrict__ scale,
                     float* __restrict__ shift)
{
    const int c = blockIdx.x;
    const float4* row = (const float4*)(Y + (size_t)c * NQ);
    float s = 0.f, ss = 0.f;
    for (int i = threadIdx.x; i < NQ / 4; i += 256) {
        float4 v = row[i];
        s  += v.x + v.y + v.z + v.w;
        ss += v.x * v.x + v.y * v.y + v.z * v.z + v.w * v.w;
    }
    #pragma unroll
    for (int off = 32; off; off >>= 1) {
        s  += __shfl_down(s, off);
        ss += __shfl_down(ss, off);
    }
    __shared__ float red[4][2];
    const int w = threadIdx.x >> 6;
    if ((threadIdx.x & 63) == 0) { red[w][0] = s; red[w][1] = ss; }
    __syncthreads();
    if (threadIdx.x == 0) {
        s  = red[0][0] + red[1][0] + red[2][0] + red[3][0];
        ss = red[0][1] + red[1][1] + red[2][1] + red[3][1];
        float mean = s * (1.f / NQ);
        float var  = ss * (1.f / NQ) - mean * mean;
        float rstd = rsqrtf(var + 1e-5f);
        float sc = g[c] * rstd;
        scale[c] = sc;
        shift[c] = bt[c] - mean * sc;
    }
}

__global__ __launch_bounds__(256)
void bn_apply_kernel(float* __restrict__ Y, const float* __restrict__ scale,
                     const float* __restrict__ shift)
{
    const int i = blockIdx.x * 256 + threadIdx.x;  // float4 index
    const int c = i >> 12;                          // NQ/4 = 4096 per channel
    float4 v = ((float4*)Y)[i];
    const float sc = scale[c], sh = shift[c];
    v.x = fmaxf(fmaf(v.x, sc, sh), 0.f);
    v.y = fmaxf(fmaf(v.y, sc, sh), 0.f);
    v.z = fmaxf(fmaf(v.z, sc, sh), 0.f);
    v.w = fmaxf(fmaf(v.w, sc, sh), 0.f);
    ((float4*)Y)[i] = v;
}

// ------------------------------------------------------------------ launch -
extern "C" void kernel_launch(void* const* d_in, const int* in_sizes, int n_in,
                              void* d_out, int out_size, void* d_ws, size_t ws_size,
                              hipStream_t stream)
{
    const float* xyz1    = (const float*)d_in[0];
    const float* xyz2    = (const float*)d_in[1];
    const int*   pid1    = (const int*)d_in[2];
    const int*   pid2    = (const int*)d_in[3];
    const float* points1 = (const float*)d_in[4];
    const float* points2 = (const float*)d_in[5];
    const float* w0      = (const float*)d_in[6];
    const float* g0      = (const float*)d_in[8];
    const float* bt0     = (const float*)d_in[9];
    const float* w1      = (const float*)d_in[10];
    const float* g1      = (const float*)d_in[12];
    const float* bt1     = (const float*)d_in[13];
    float* out = (float*)d_out;

    char* ws = (char*)d_ws;
    int*   idxb   = (int*)(ws + 0);                       // 196608 B
    float* wb     = (float*)(ws + 196608);                // 196608 B
    float* interp = (float*)(ws + 393216);                // 16 MB
    float* y0     = (float*)(ws + 393216 + 16777216);     // 16 MB
    float* sc0    = (float*)(ws + 393216 + 2 * 16777216);
    float* sh0    = sc0 + NCH;
    float* sc1    = sh0 + NCH;
    float* sh1    = sc1 + NCH;

    knn_kernel<<<NQ / QB, 512, 0, stream>>>(xyz1, xyz2, pid1, pid2, idxb, wb);
    interp_kernel<<<dim3(NQ / 256, NCH), 256, 0, stream>>>(points2, idxb, wb, interp);
    gemm_kernel<512, true, false><<<256, 256, 0, stream>>>(w0, points1, interp, nullptr, nullptr, y0);
    bn_stats_kernel<<<NCH, 256, 0, stream>>>(y0, g0, bt0, sc0, sh0);
    // BN1 apply + relu folded into GEMM2's B staging
    gemm_kernel<256, false, true><<<256, 256, 0, stream>>>(w1, y0, nullptr, sc0, sh0, out);
    bn_stats_kernel<<<NCH, 256, 0, stream>>>(out, g1, bt1, sc1, sh1);
    bn_apply_kernel<<<(NCH * NQ / 4) / 256, 256, 0, stream>>>(out, sc1, sh1);
}

// Round 3
// 235.936 us; speedup vs baseline: 1.5992x; 1.2912x over previous
//
#include <hip/hip_runtime.h>
#include <math.h>

#define NQ 16384
#define NS 4096
#define NCH 256
#define BIGD 1e8f
#define EPSW 1e-8f

typedef __attribute__((ext_vector_type(8))) short short8;
typedef __attribute__((ext_vector_type(4))) float f32x4;

static __device__ __forceinline__ unsigned short f2bf(float x) {
    unsigned u = __float_as_uint(x);
    unsigned r = (u + 0x7fff + ((u >> 16) & 1)) >> 16;   // RNE
    return (unsigned short)r;
}

// ---------------------------------------------------------------- KNN ------
#define QB 32
#define SS 16
#define PPT (NS / SS)
#define CSTRIDE (SS * 3 + 1)

__global__ __launch_bounds__(512)
void knn_kernel(const float* __restrict__ xyz1, const float* __restrict__ xyz2,
                const int* __restrict__ pid1, const int* __restrict__ pid2,
                int* __restrict__ oidx, float* __restrict__ ow)
{
    __shared__ float4 sp[NS];
    const int tid = threadIdx.x;
    #pragma unroll
    for (int j = 0; j < 8; ++j) {
        const int i = tid + j * 512;
        sp[i] = make_float4(xyz2[i], xyz2[NS + i], xyz2[2 * NS + i],
                            __int_as_float(pid2[i]));
    }
    __syncthreads();

    const int ql = tid & 31;
    const int part = tid >> 5;
    const int q = blockIdx.x * QB + ql;
    const float qx = xyz1[q], qy = xyz1[NQ + q], qz = xyz1[2 * NQ + q];
    const int qid = pid1[q];

    float e0 = INFINITY, e1 = INFINITY, e2 = INFINITY;
    int j0 = 0, j1 = 0, j2 = 0;
    const int sBeg = part * PPT;
    #pragma unroll 4
    for (int i = 0; i < PPT; ++i) {
        const int s = sBeg + i;
        float4 p = sp[s];
        float dx = p.x - qx, dy = p.y - qy, dz = p.z - qz;
        float d = fmaf(dx, dx, fmaf(dy, dy, dz * dz));
        if (__float_as_int(p.w) != qid) d = INFINITY;
        const bool m0 = d < e0, m1 = d < e1, m2 = d < e2;
        const float ne2 = m1 ? e1 : d;  const int nj2 = m1 ? j1 : s;
        const float ne1 = m0 ? e0 : d;  const int nj1 = m0 ? j0 : s;
        e2 = m2 ? ne2 : e2;  j2 = m2 ? nj2 : j2;
        e1 = m1 ? ne1 : e1;  j1 = m1 ? nj1 : j1;
        e0 = m0 ? d : e0;    j0 = m0 ? s : j0;
    }
    __syncthreads();
    float2* cand = (float2*)sp;
    const int cb = ql * CSTRIDE + part * 3;
    cand[cb + 0] = make_float2(e0, __int_as_float(j0));
    cand[cb + 1] = make_float2(e1, __int_as_float(j1));
    cand[cb + 2] = make_float2(e2, __int_as_float(j2));
    __syncthreads();

    if (tid < QB) {
        e0 = e1 = e2 = INFINITY; j0 = j1 = j2 = 0;
        const float2* row = cand + tid * CSTRIDE;
        for (int p = 0; p < SS; ++p) {
            #pragma unroll
            for (int k = 0; k < 3; ++k) {
                float2 c = row[p * 3 + k];
                const float d = c.x; const int s = __float_as_int(c.y);
                const bool m0 = d < e0, m1 = d < e1, m2 = d < e2;
                const float ne2 = m1 ? e1 : d;  const int nj2 = m1 ? j1 : s;
                const float ne1 = m0 ? e0 : d;  const int nj1 = m0 ? j0 : s;
                e2 = m2 ? ne2 : e2;  j2 = m2 ? nj2 : j2;
                e1 = m1 ? ne1 : e1;  j1 = m1 ? nj1 : j1;
                e0 = m0 ? d : e0;    j0 = m0 ? s : j0;
            }
        }
        if (isinf(e0)) { j0 = 0;  e0 = BIGD; }
        if (isinf(e1)) { j1 = j0; e1 = BIGD; }
        if (isinf(e2)) { j2 = j0; e2 = BIGD; }
        const float w0 = 1.f / (e0 + EPSW), w1 = 1.f / (e1 + EPSW), w2 = 1.f / (e2 + EPSW);
        const float inv = 1.f / (w0 + w1 + w2);
        const int qg = blockIdx.x * QB + tid;
        oidx[qg * 3 + 0] = j0; oidx[qg * 3 + 1] = j1; oidx[qg * 3 + 2] = j2;
        ow[qg * 3 + 0] = w0 * inv; ow[qg * 3 + 1] = w1 * inv; ow[qg * 3 + 2] = w2 * inv;
    }
}

// --------------------------------------------------------- interpolation ---
__global__ __launch_bounds__(256)
void interp_kernel(const float* __restrict__ points2, const int* __restrict__ oidx,
                   const float* __restrict__ ow, float* __restrict__ interp)
{
    const int n = blockIdx.x * 256 + threadIdx.x;
    const int d = blockIdx.y;
    const int i0 = oidx[n * 3 + 0], i1 = oidx[n * 3 + 1], i2 = oidx[n * 3 + 2];
    const float w0 = ow[n * 3 + 0], w1 = ow[n * 3 + 1], w2 = ow[n * 3 + 2];
    const float* row = points2 + (size_t)d * NS;
    interp[(size_t)d * NQ + n] = w0 * row[i0] + w1 * row[i1] + w2 * row[i2];
}

// ----------------------------------------------- weight fp32 -> bf16 -------
__global__ __launch_bounds__(256)
void cvtw_kernel(const float* __restrict__ src, unsigned short* __restrict__ dst)
{
    const int i = blockIdx.x * 256 + threadIdx.x;
    float4 v = ((const float4*)src)[i];
    ushort4 o;
    o.x = f2bf(v.x); o.y = f2bf(v.y); o.z = f2bf(v.z); o.w = f2bf(v.w);
    ((ushort4*)dst)[i] = o;
}

// ------------------------------------- [C][N] fp32 -> Xt[N][KTOT] bf16 -----
// 64x64 tile transpose+convert via LDS.
__global__ __launch_bounds__(256)
void tcvt_kernel(const float* __restrict__ src, unsigned short* __restrict__ Xt,
                 int coff, int KTOT)
{
    __shared__ float tile[64][65];
    const int cb = blockIdx.x * 64;      // channel base in src
    const int nb = blockIdx.y * 64;      // point base
    #pragma unroll
    for (int rnd = 0; rnd < 4; ++rnd) {
        const int r = rnd * 16 + (threadIdx.x >> 4);
        const int c4 = (threadIdx.x & 15) * 4;
        float4 v = *(const float4*)&src[(size_t)(cb + r) * NQ + nb + c4];
        tile[r][c4 + 0] = v.x; tile[r][c4 + 1] = v.y;
        tile[r][c4 + 2] = v.z; tile[r][c4 + 3] = v.w;
    }
    __syncthreads();
    #pragma unroll
    for (int half = 0; half < 2; ++half) {
        const int p  = (threadIdx.x >> 3) + half * 32;   // point in tile
        const int cg = threadIdx.x & 7;                  // 8-channel group
        ushort4 o0, o1;
        o0.x = f2bf(tile[cg * 8 + 0][p]); o0.y = f2bf(tile[cg * 8 + 1][p]);
        o0.z = f2bf(tile[cg * 8 + 2][p]); o0.w = f2bf(tile[cg * 8 + 3][p]);
        o1.x = f2bf(tile[cg * 8 + 4][p]); o1.y = f2bf(tile[cg * 8 + 5][p]);
        o1.z = f2bf(tile[cg * 8 + 6][p]); o1.w = f2bf(tile[cg * 8 + 7][p]);
        ushort4* dst = (ushort4*)&Xt[(size_t)(nb + p) * KTOT + coff + cb + cg * 8];
        dst[0] = o0; dst[1] = o1;
    }
}

// ------------------------------------------------------------- MFMA GEMM ---
// C = W[256][K] @ X[K][N], X given as Xt[N][K] bf16. Block: 32-point slab,
// full K staged once in LDS (XOR-swizzled via pre-swizzled global source).
// 4 waves stacked in M (64 rows each). A-fragments straight from L2.
// TOUT: C stored as [N][256] (transposed), else [256][NQ].
template<int K, bool TOUT>
__global__ __launch_bounds__(256)
void mgemm_kernel(const unsigned short* __restrict__ Wb,
                  const unsigned short* __restrict__ Xt,
                  float* __restrict__ C)
{
    constexpr int K2 = K * 2;                     // row bytes
    __shared__ unsigned char sB[32 * K2];
    const int tid = threadIdx.x;
    const int n0 = blockIdx.x * 32;

    constexpr int ROUNDS = (32 * K2 / 16) / 256;
    #pragma unroll
    for (int j = 0; j < ROUNDS; ++j) {
        const int p   = (j * 256 + tid) * 16;     // linear LDS byte
        const int row = p >> (K == 512 ? 10 : 9);
        const int c   = p & (K2 - 1);
        const int q   = c ^ ((row & 7) << 4);     // inverse-swizzle source
        const char* g = (const char*)(Xt + (size_t)(n0 + row) * K) + q;
        __builtin_amdgcn_global_load_lds(
            (const __attribute__((address_space(1))) void*)g,
            (__attribute__((address_space(3))) void*)(sB + p), 16, 0, 0);
    }
    __syncthreads();

    const int w = tid >> 6, l = tid & 63;
    const int lr = l & 15, lk = l >> 4;
    f32x4 acc[4][2] = {};
    #pragma unroll
    for (int ks = 0; ks < K / 32; ++ks) {
        short8 b[2];
        #pragma unroll
        for (int nf = 0; nf < 2; ++nf) {
            const int r  = nf * 16 + lr;
            const int cbyte = ks * 64 + lk * 16;
            b[nf] = *(const short8*)&sB[r * K2 + (cbyte ^ ((r & 7) << 4))];
        }
        #pragma unroll
        for (int mf = 0; mf < 4; ++mf) {
            const int m = w * 64 + mf * 16 + lr;
            const short8 a = *(const short8*)&Wb[(size_t)m * K + ks * 32 + lk * 8];
            #pragma unroll
            for (int nf = 0; nf < 2; ++nf)
                acc[mf][nf] = __builtin_amdgcn_mfma_f32_16x16x32_bf16(
                                  a, b[nf], acc[mf][nf], 0, 0, 0);
        }
    }
    #pragma unroll
    for (int mf = 0; mf < 4; ++mf)
        #pragma unroll
        for (int nf = 0; nf < 2; ++nf) {
            if (TOUT) {
                const int n = n0 + nf * 16 + lr;
                const int m = w * 64 + mf * 16 + lk * 4;
                *(f32x4*)&C[(size_t)n * 256 + m] = acc[mf][nf];
            } else {
                #pragma unroll
                for (int r2 = 0; r2 < 4; ++r2) {
                    const int m = w * 64 + mf * 16 + lk * 4 + r2;
                    const int n = n0 + nf * 16 + lr;
                    C[(size_t)m * NQ + n] = acc[mf][nf][r2];
                }
            }
        }
}

// ------------------------------------------- BN over y0T [N][256] ----------
__global__ __launch_bounds__(256)
void colstats_kernel(const float* __restrict__ Y, float* __restrict__ sum,
                     float* __restrict__ sumsq)
{
    const int c = threadIdx.x;
    const int r0 = blockIdx.x * 64;
    float s = 0.f, ss = 0.f;
    for (int r = 0; r < 64; ++r) {
        float v = Y[(size_t)(r0 + r) * 256 + c];
        s += v; ss += v * v;
    }
    atomicAdd(&sum[c], s);
    atomicAdd(&sumsq[c], ss);
}

__global__ void bnfin_kernel(const float* __restrict__ sum, const float* __restrict__ sumsq,
                             const float* __restrict__ g, const float* __restrict__ bt,
                             float* __restrict__ sc, float* __restrict__ sh)
{
    const int c = threadIdx.x;
    float mean = sum[c] * (1.f / NQ);
    float var  = sumsq[c] * (1.f / NQ) - mean * mean;
    float rs = rsqrtf(var + 1e-5f);
    float s = g[c] * rs;
    sc[c] = s; sh[c] = bt[c] - mean * s;
}

// bn-apply + relu + bf16 convert: y0T [N][256] fp32 -> X2t [N][256] bf16
__global__ __launch_bounds__(256)
void bnacvt_kernel(const float* __restrict__ Y, const float* __restrict__ sc,
                   const float* __restrict__ sh, unsigned short* __restrict__ X)
{
    const int i = blockIdx.x * 256 + threadIdx.x;   // float4 index
    const int c = (i & 63) * 4;
    float4 v = ((const float4*)Y)[i];
    float4 s = *(const float4*)&sc[c];
    float4 h = *(const float4*)&sh[c];
    ushort4 o;
    o.x = f2bf(fmaxf(fmaf(v.x, s.x, h.x), 0.f));
    o.y = f2bf(fmaxf(fmaf(v.y, s.y, h.y), 0.f));
    o.z = f2bf(fmaxf(fmaf(v.z, s.z, h.z), 0.f));
    o.w = f2bf(fmaxf(fmaf(v.w, s.w, h.w), 0.f));
    ((ushort4*)X)[i] = o;
}

// ---------------------------------------- BN over out [256][NQ] (layer 2) --
__global__ __launch_bounds__(256)
void bn_stats_kernel(const float* __restrict__ Y, const float* __restrict__ g,
                     const float* __restrict__ bt, float* __restrict__ scale,
                     float* __restrict__ shift)
{
    const int c = blockIdx.x;
    const float4* row = (const float4*)(Y + (size_t)c * NQ);
    float s = 0.f, ss = 0.f;
    for (int i = threadIdx.x; i < NQ / 4; i += 256) {
        float4 v = row[i];
        s  += v.x + v.y + v.z + v.w;
        ss += v.x * v.x + v.y * v.y + v.z * v.z + v.w * v.w;
    }
    #pragma unroll
    for (int off = 32; off; off >>= 1) {
        s  += __shfl_down(s, off);
        ss += __shfl_down(ss, off);
    }
    __shared__ float red[4][2];
    const int w = threadIdx.x >> 6;
    if ((threadIdx.x & 63) == 0) { red[w][0] = s; red[w][1] = ss; }
    __syncthreads();
    if (threadIdx.x == 0) {
        s  = red[0][0] + red[1][0] + red[2][0] + red[3][0];
        ss = red[0][1] + red[1][1] + red[2][1] + red[3][1];
        float mean = s * (1.f / NQ);
        float var  = ss * (1.f / NQ) - mean * mean;
        float rstd = rsqrtf(var + 1e-5f);
        float sc = g[c] * rstd;
        scale[c] = sc;
        shift[c] = bt[c] - mean * sc;
    }
}

__global__ __launch_bounds__(256)
void bn_apply_kernel(float* __restrict__ Y, const float* __restrict__ scale,
                     const float* __restrict__ shift)
{
    const int i = blockIdx.x * 256 + threadIdx.x;
    const int c = i >> 12;
    float4 v = ((float4*)Y)[i];
    const float sc = scale[c], sh = shift[c];
    v.x = fmaxf(fmaf(v.x, sc, sh), 0.f);
    v.y = fmaxf(fmaf(v.y, sc, sh), 0.f);
    v.z = fmaxf(fmaf(v.z, sc, sh), 0.f);
    v.w = fmaxf(fmaf(v.w, sc, sh), 0.f);
    ((float4*)Y)[i] = v;
}

// ------------------------------------------------------------------ launch -
extern "C" void kernel_launch(void* const* d_in, const int* in_sizes, int n_in,
                              void* d_out, int out_size, void* d_ws, size_t ws_size,
                              hipStream_t stream)
{
    const float* xyz1    = (const float*)d_in[0];
    const float* xyz2    = (const float*)d_in[1];
    const int*   pid1    = (const int*)d_in[2];
    const int*   pid2    = (const int*)d_in[3];
    const float* points1 = (const float*)d_in[4];
    const float* points2 = (const float*)d_in[5];
    const float* w0      = (const float*)d_in[6];
    const float* g0      = (const float*)d_in[8];
    const float* bt0     = (const float*)d_in[9];
    const float* w1      = (const float*)d_in[10];
    const float* g1      = (const float*)d_in[12];
    const float* bt1     = (const float*)d_in[13];
    float* out = (float*)d_out;

    char* ws = (char*)d_ws;
    int*            idxb  = (int*)(ws + 0);                 // 196608
    float*          wb    = (float*)(ws + 196608);          // 196608
    unsigned short* Wb0   = (unsigned short*)(ws + 393216); // 262144
    unsigned short* Wb1   = (unsigned short*)(ws + 655360); // 131072
    float*          sum0  = (float*)(ws + 786432);          // 1024
    float*          sq0   = (float*)(ws + 787456);          // 1024
    float*          sc0   = (float*)(ws + 788480);
    float*          sh0   = (float*)(ws + 789504);
    float*          sc1   = (float*)(ws + 790528);
    float*          sh1   = (float*)(ws + 791552);
    float*          bufA  = (float*)(ws + 1048576);         // 16MB: interp, then y0T
    unsigned short* bufB  = (unsigned short*)(ws + 1048576 + 16777216); // 16MB: Xt, then X2t

    float*          interp = bufA;
    float*          y0T    = bufA;
    unsigned short* Xt     = bufB;
    unsigned short* X2t    = bufB;

    knn_kernel<<<NQ / QB, 512, 0, stream>>>(xyz1, xyz2, pid1, pid2, idxb, wb);
    cvtw_kernel<<<(256 * 512 / 4) / 256, 256, 0, stream>>>(w0, Wb0);
    cvtw_kernel<<<(256 * 256 / 4) / 256, 256, 0, stream>>>(w1, Wb1);
    interp_kernel<<<dim3(NQ / 256, NCH), 256, 0, stream>>>(points2, idxb, wb, interp);
    tcvt_kernel<<<dim3(4, NQ / 64), 256, 0, stream>>>(points1, Xt, 0, 512);
    tcvt_kernel<<<dim3(4, NQ / 64), 256, 0, stream>>>(interp, Xt, 256, 512);
    mgemm_kernel<512, true><<<NQ / 32, 256, 0, stream>>>(Wb0, Xt, y0T);
    hipMemsetAsync(sum0, 0, 2048, stream);                  // sum0 + sq0
    colstats_kernel<<<NQ / 64, 256, 0, stream>>>(y0T, sum0, sq0);
    bnfin_kernel<<<1, 256, 0, stream>>>(sum0, sq0, g0, bt0, sc0, sh0);
    bnacvt_kernel<<<(NQ * 256 / 4) / 256, 256, 0, stream>>>(y0T, sc0, sh0, X2t);
    mgemm_kernel<256, false><<<NQ / 32, 256, 0, stream>>>(Wb1, X2t, out);
    bn_stats_kernel<<<NCH, 256, 0, stream>>>(out, g1, bt1, sc1, sh1);
    bn_apply_kernel<<<(NCH * NQ / 4) / 256, 256, 0, stream>>>(out, sc1, sh1);
}